// Round 5
// baseline (1861.594 us; speedup 1.0000x reference)
//
#include <hip/hip_runtime.h>
#include <hip/hip_bf16.h>

// MHA, softmax over model-dim AFTER A@V => plain accumulation, no online softmax.
// Round 5 == round 4 (bench never ran: GPU acquisition timeout; no signal).
// OUTPUT IS FP32 (reference returns fp32; harness reads d_out per the
// reference's output dtype — the "(bf16,...)" label text is hard-coded, not a
// signal). Rounds 2/3's exact-1.0 absmax = packed-bf16 stores read as fp32
// against a near-one-hot reference. Inputs fp32 (proven by round-1 NaN +
// incompressible 5.35MB npz). Compute fp32. ws sliced (<=25.2MB) per round 3.

#define NB 4
#define NS 2048
#define ND 128
#define NH 8

typedef unsigned short u16;
typedef unsigned int u32;

// ---------------------------------------------------------------------------
// Projection slice: batch b0, heads [h0, h0+nh). Writes ws tensors laid out as
// [hh, s, d] (hh = local head). GEMM tile 64x64, K=128 staged in halves.
// blockIdx.z selects W_q / W_k / W_v.
// ---------------------------------------------------------------------------
__global__ __launch_bounds__(256) void proj_kernel(
    const float* __restrict__ xg, const float* __restrict__ Wqg,
    const float* __restrict__ Wkg, const float* __restrict__ Wvg,
    float* __restrict__ Qw, float* __restrict__ Kw, float* __restrict__ Vw,
    int b0, int h0)
{
    __shared__ float xsT[64][68];   // [k][m] transposed, padded
    __shared__ float wsT[64][68];   // [k][e]

    const int which = blockIdx.z;
    const float* __restrict__ W = (which == 0) ? Wqg : (which == 1) ? Wkg : Wvg;
    float* __restrict__ outp    = (which == 0) ? Qw  : (which == 1) ? Kw  : Vw;

    const int tid = threadIdx.x;
    const int sL0 = blockIdx.x * 64;          // local s tile (0..2047)
    const int eL0 = blockIdx.y * 64;          // local e tile (0..nh*128)
    const int mG0 = b0 * NS + sL0;            // global x row
    const int eG0 = h0 * ND + eL0;            // global W row

    const int tr = tid >> 4;   // 0..15
    const int tc = tid & 15;   // 0..15

    float acc[4][4];
    #pragma unroll
    for (int i = 0; i < 4; ++i)
        #pragma unroll
        for (int j = 0; j < 4; ++j) acc[i][j] = 0.f;

    for (int kk = 0; kk < 2; ++kk) {
        __syncthreads();
        #pragma unroll
        for (int i = 0; i < 4; ++i) {
            int f  = tid + i * 256;      // 0..1023 float4 units
            int r  = f & 63;
            int kg = f >> 6;             // 0..15
            float4 xv = *(const float4*)&xg[(size_t)(mG0 + r) * ND + kk * 64 + kg * 4];
            xsT[kg * 4 + 0][r] = xv.x;
            xsT[kg * 4 + 1][r] = xv.y;
            xsT[kg * 4 + 2][r] = xv.z;
            xsT[kg * 4 + 3][r] = xv.w;
            float4 wv = *(const float4*)&W[(size_t)(eG0 + r) * ND + kk * 64 + kg * 4];
            wsT[kg * 4 + 0][r] = wv.x;
            wsT[kg * 4 + 1][r] = wv.y;
            wsT[kg * 4 + 2][r] = wv.z;
            wsT[kg * 4 + 3][r] = wv.w;
        }
        __syncthreads();
        #pragma unroll 4
        for (int k = 0; k < 64; ++k) {
            const float4 a = *(const float4*)&xsT[k][tr * 4];
            const float4 b = *(const float4*)&wsT[k][tc * 4];
            acc[0][0] += a.x * b.x; acc[0][1] += a.x * b.y; acc[0][2] += a.x * b.z; acc[0][3] += a.x * b.w;
            acc[1][0] += a.y * b.x; acc[1][1] += a.y * b.y; acc[1][2] += a.y * b.z; acc[1][3] += a.y * b.w;
            acc[2][0] += a.z * b.x; acc[2][1] += a.z * b.y; acc[2][2] += a.z * b.z; acc[2][3] += a.z * b.w;
            acc[3][0] += a.w * b.x; acc[3][1] += a.w * b.y; acc[3][2] += a.w * b.z; acc[3][3] += a.w * b.w;
        }
    }

    // write ws [hh][s][d]
    #pragma unroll
    for (int i = 0; i < 4; ++i) {
        int sL = sL0 + tr * 4 + i;
        int eL = eL0 + tc * 4;
        int hh = eL >> 7;          // /128 (4tc+3 stays within one head tile)
        int d  = eL & 127;
        float4 st;
        st.x = acc[i][0]; st.y = acc[i][1]; st.z = acc[i][2]; st.w = acc[i][3];
        *(float4*)&outp[((size_t)hh * NS + sL) * ND + d] = st;
    }
}

// ---------------------------------------------------------------------------
// Attention slice: 32 q-rows of local head hh = blockIdx.y of slice (b0,h0).
// Z' = (Q K^T * scale) @ V accumulated over 64 t-tiles of 32, then softmax
// over D=128 per row, fp32 store to out[b0*NH+h0+hh].
// ---------------------------------------------------------------------------
__global__ __launch_bounds__(256) void attn_kernel(
    const float* __restrict__ Qw, const float* __restrict__ Kw,
    const float* __restrict__ Vw, float* __restrict__ outg, int b0, int h0)
{
    __shared__ float QsT[128][36];  // [k][q]
    __shared__ float KsT[128][36];  // [k][t]
    __shared__ float Vs[32][132];   // [t][d]
    __shared__ float As[32][40];    // [q][t]

    const int tid = threadIdx.x;
    const int q0 = blockIdx.x * 32;
    const int hh = blockIdx.y;
    const size_t wbase = (size_t)hh * NS * ND;                    // ws base
    const size_t obase = (size_t)(b0 * NH + h0 + hh) * NS * ND;   // out base

    // stage Q chunk transposed (once)
    #pragma unroll
    for (int i = 0; i < 4; ++i) {
        int f  = tid + i * 256;        // 0..1023 float4 units
        int r  = f & 31;
        int kg = f >> 5;               // 0..31
        float4 qv = *(const float4*)&Qw[wbase + (size_t)(q0 + r) * ND + kg * 4];
        QsT[kg * 4 + 0][r] = qv.x;
        QsT[kg * 4 + 1][r] = qv.y;
        QsT[kg * 4 + 2][r] = qv.z;
        QsT[kg * 4 + 3][r] = qv.w;
    }

    const int tr = tid >> 4;   // 0..15
    const int tc = tid & 15;   // 0..15

    float acc0[8], acc1[8];    // rows tr and tr+16, cols tc*8..tc*8+7
    #pragma unroll
    for (int j = 0; j < 8; ++j) { acc0[j] = 0.f; acc1[j] = 0.f; }

    const float scale = 0.08838834764831845f;  // 1/sqrt(128)

    for (int tt = 0; tt < 64; ++tt) {
        const int t0 = tt * 32;
        __syncthreads();  // previous AV done before restage
        #pragma unroll
        for (int i = 0; i < 4; ++i) {
            int f  = tid + i * 256;
            int r  = f & 31;
            int kg = f >> 5;
            float4 kv = *(const float4*)&Kw[wbase + (size_t)(t0 + r) * ND + kg * 4];
            KsT[kg * 4 + 0][r] = kv.x;
            KsT[kg * 4 + 1][r] = kv.y;
            KsT[kg * 4 + 2][r] = kv.z;
            KsT[kg * 4 + 3][r] = kv.w;
            int r2 = f >> 5;           // 0..31
            int d0 = (f & 31) * 4;
            float4 vv = *(const float4*)&Vw[wbase + (size_t)(t0 + r2) * ND + d0];
            *(float4*)&Vs[r2][d0] = vv;
        }
        __syncthreads();

        // QK^T 32x32 tile, 2x2 per thread
        float s00 = 0.f, s01 = 0.f, s10 = 0.f, s11 = 0.f;
        #pragma unroll 8
        for (int k = 0; k < 128; ++k) {
            const float2 qv = *(const float2*)&QsT[k][tr * 2];
            const float2 kv = *(const float2*)&KsT[k][tc * 2];
            s00 += qv.x * kv.x; s01 += qv.x * kv.y;
            s10 += qv.y * kv.x; s11 += qv.y * kv.y;
        }
        As[tr * 2 + 0][tc * 2 + 0] = s00 * scale;
        As[tr * 2 + 0][tc * 2 + 1] = s01 * scale;
        As[tr * 2 + 1][tc * 2 + 0] = s10 * scale;
        As[tr * 2 + 1][tc * 2 + 1] = s11 * scale;
        __syncthreads();

        // Z' += A(32x32) @ V(32x128)
        #pragma unroll 4
        for (int t = 0; t < 32; ++t) {
            const float a0 = As[tr][t];
            const float a1 = As[tr + 16][t];
            const float4 v0 = *(const float4*)&Vs[t][tc * 8];
            const float4 v1 = *(const float4*)&Vs[t][tc * 8 + 4];
            acc0[0] += a0 * v0.x; acc0[1] += a0 * v0.y; acc0[2] += a0 * v0.z; acc0[3] += a0 * v0.w;
            acc0[4] += a0 * v1.x; acc0[5] += a0 * v1.y; acc0[6] += a0 * v1.z; acc0[7] += a0 * v1.w;
            acc1[0] += a1 * v0.x; acc1[1] += a1 * v0.y; acc1[2] += a1 * v0.z; acc1[3] += a1 * v0.w;
            acc1[4] += a1 * v1.x; acc1[5] += a1 * v1.y; acc1[6] += a1 * v1.z; acc1[7] += a1 * v1.w;
        }
    }

    // softmax over D=128 per row; 16-lane aligned groups share a row
    float m0 = acc0[0], m1 = acc1[0];
    #pragma unroll
    for (int j = 1; j < 8; ++j) { m0 = fmaxf(m0, acc0[j]); m1 = fmaxf(m1, acc1[j]); }
    #pragma unroll
    for (int off = 1; off < 16; off <<= 1) {
        m0 = fmaxf(m0, __shfl_xor(m0, off, 64));
        m1 = fmaxf(m1, __shfl_xor(m1, off, 64));
    }
    float sum0 = 0.f, sum1 = 0.f;
    float p0[8], p1[8];
    #pragma unroll
    for (int j = 0; j < 8; ++j) {
        p0[j] = expf(acc0[j] - m0); sum0 += p0[j];
        p1[j] = expf(acc1[j] - m1); sum1 += p1[j];
    }
    #pragma unroll
    for (int off = 1; off < 16; off <<= 1) {
        sum0 += __shfl_xor(sum0, off, 64);
        sum1 += __shfl_xor(sum1, off, 64);
    }
    const float inv0 = 1.f / sum0, inv1 = 1.f / sum1;

    // fp32 output, two float4 per row-half per thread (fully coalesced)
    float4 o;
    o.x = p0[0] * inv0; o.y = p0[1] * inv0; o.z = p0[2] * inv0; o.w = p0[3] * inv0;
    *(float4*)&outg[obase + (size_t)(q0 + tr) * ND + tc * 8] = o;
    o.x = p0[4] * inv0; o.y = p0[5] * inv0; o.z = p0[6] * inv0; o.w = p0[7] * inv0;
    *(float4*)&outg[obase + (size_t)(q0 + tr) * ND + tc * 8 + 4] = o;
    o.x = p1[0] * inv1; o.y = p1[1] * inv1; o.z = p1[2] * inv1; o.w = p1[3] * inv1;
    *(float4*)&outg[obase + (size_t)(q0 + tr + 16) * ND + tc * 8] = o;
    o.x = p1[4] * inv1; o.y = p1[5] * inv1; o.z = p1[6] * inv1; o.w = p1[7] * inv1;
    *(float4*)&outg[obase + (size_t)(q0 + tr + 16) * ND + tc * 8 + 4] = o;
}

extern "C" void kernel_launch(void* const* d_in, const int* in_sizes, int n_in,
                              void* d_out, int out_size, void* d_ws, size_t ws_size,
                              hipStream_t stream)
{
    (void)out_size;
    // identify x by element count (insurance against input-order surprises)
    int xi = 0;
    for (int i = 0; i < n_in && i < 4; ++i)
        if (in_sizes[i] == NB * NS * ND) { xi = i; break; }
    const float* x = (const float*)d_in[xi];
    const float* Ws[3]; int w = 0;
    for (int i = 0; i < 4; ++i) if (i != xi) Ws[w++] = (const float*)d_in[i];
    const float* Wq = Ws[0];
    const float* Wk = Ws[1];
    const float* Wv = Ws[2];
    float* out = (float*)d_out;

    // slice size chosen from ws_size: per-(b,h) footprint = 3 * 2048*128*4 B
    const size_t PBH = (size_t)3 * NS * ND * 4;        // 3,145,728 B
    int nh = (ws_size >= 8 * PBH) ? 8 : (ws_size >= 2 * PBH) ? 2 : 1;

    const size_t tens = (size_t)nh * NS * ND;          // elems per ws tensor
    float* Q = (float*)d_ws;
    float* K = Q + tens;
    float* V = K + tens;

    for (int b0 = 0; b0 < NB; ++b0) {
        for (int h0 = 0; h0 < NH; h0 += nh) {
            proj_kernel<<<dim3(NS / 64, nh * 2, 3), dim3(256), 0, stream>>>(
                x, Wq, Wk, Wv, Q, K, V, b0, h0);
            attn_kernel<<<dim3(NS / 32, nh), dim3(256), 0, stream>>>(
                Q, K, V, out, b0, h0);
        }
    }
}

// Round 6
// 349.810 us; speedup vs baseline: 5.3217x; 5.3217x over previous
//
#include <hip/hip_runtime.h>
#include <hip/hip_bf16.h>

// MHA, softmax over model-dim AFTER A@V => plain accumulation, no online softmax.
// Round 6: MFMA attention with fp32->bf16 hi/lo split (3-MFMA products).
// Proj (fp32 VALU GEMM, verified) now emits FRAGMENT-ORDERED bf16 hi/lo Q/K/V
// so attention's LDS staging is a linear coalesced copy, conflict-free reads.
// fp32 in, fp32 out (proven round 5), ws-adaptive slicing kept.

#define NB 4
#define NS 2048
#define ND 128
#define NH 8
#define EPB (NS * ND)   // 262144 elems per (b,h)

typedef unsigned short u16;
typedef unsigned int u32;
typedef short bf16x8 __attribute__((ext_vector_type(8)));
typedef float f32x4 __attribute__((ext_vector_type(4)));

struct __align__(8) us4 { u16 a, b, c, d; };

__device__ __forceinline__ void splitf(float f, u16& hi, u16& lo) {
    u32 fb = __float_as_uint(f);
    u32 hb = fb + 0x7FFFu + ((fb >> 16) & 1u);      // RNE to bf16
    hi = (u16)(hb >> 16);
    float fh = __uint_as_float((hb >> 16) << 16);
    float fl = f - fh;                               // exact residual
    u32 lb = __float_as_uint(fl);
    u32 lr = lb + 0x7FFFu + ((lb >> 16) & 1u);
    lo = (u16)(lr >> 16);
}

// ---------------------------------------------------------------------------
// Projection: fp32 GEMM (verified structure), epilogue splits acc to bf16
// hi/lo and scatter-stores into MFMA-fragment-ordered ws tensors:
//   Qf[q>>4][kc][lane][j]           lane=g*16+c: c=q&15, (kc,g,j)=d-pos
//   Kf[T][kc][nt][lane][j]          c=t&15, nt=(t>>4)&1, T=t>>5
//   Vf[T][ni][lane][j]              lane: c=d&15, g=(t>>3)&3, j=t&7, ni=d>>4
// ---------------------------------------------------------------------------
__global__ __launch_bounds__(256) void proj_kernel(
    const float* __restrict__ xg, const float* __restrict__ Wqg,
    const float* __restrict__ Wkg, const float* __restrict__ Wvg,
    u16* __restrict__ ws, int b0, int nbh)
{
    __shared__ float xsT[64][68];
    __shared__ float wsT[64][68];

    const int which = blockIdx.z;
    const float* __restrict__ W = (which == 0) ? Wqg : (which == 1) ? Wkg : Wvg;

    const int tid = threadIdx.x;
    const int bgl = blockIdx.x >> 5;               // batch within slice
    const int sL0 = (blockIdx.x & 31) * 64;        // s tile
    const int eL0 = blockIdx.y * 64;               // e tile (all heads)
    const int mG0 = (b0 + bgl) * NS + sL0;
    const int tr = tid >> 4;
    const int tc = tid & 15;

    float acc[4][4];
    #pragma unroll
    for (int i = 0; i < 4; ++i)
        #pragma unroll
        for (int j = 0; j < 4; ++j) acc[i][j] = 0.f;

    for (int kk = 0; kk < 2; ++kk) {
        __syncthreads();
        #pragma unroll
        for (int i = 0; i < 4; ++i) {
            int f  = tid + i * 256;
            int r  = f & 63;
            int kg = f >> 6;
            float4 xv = *(const float4*)&xg[(size_t)(mG0 + r) * ND + kk * 64 + kg * 4];
            xsT[kg * 4 + 0][r] = xv.x;
            xsT[kg * 4 + 1][r] = xv.y;
            xsT[kg * 4 + 2][r] = xv.z;
            xsT[kg * 4 + 3][r] = xv.w;
            float4 wv = *(const float4*)&W[(size_t)(eL0 + r) * ND + kk * 64 + kg * 4];
            wsT[kg * 4 + 0][r] = wv.x;
            wsT[kg * 4 + 1][r] = wv.y;
            wsT[kg * 4 + 2][r] = wv.z;
            wsT[kg * 4 + 3][r] = wv.w;
        }
        __syncthreads();
        #pragma unroll 4
        for (int k = 0; k < 64; ++k) {
            const float4 a = *(const float4*)&xsT[k][tr * 4];
            const float4 b = *(const float4*)&wsT[k][tc * 4];
            acc[0][0] += a.x * b.x; acc[0][1] += a.x * b.y; acc[0][2] += a.x * b.z; acc[0][3] += a.x * b.w;
            acc[1][0] += a.y * b.x; acc[1][1] += a.y * b.y; acc[1][2] += a.y * b.z; acc[1][3] += a.y * b.w;
            acc[2][0] += a.z * b.x; acc[2][1] += a.z * b.y; acc[2][2] += a.z * b.z; acc[2][3] += a.z * b.w;
            acc[3][0] += a.w * b.x; acc[3][1] += a.w * b.y; acc[3][2] += a.w * b.z; acc[3][3] += a.w * b.w;
        }
    }

    // split all 16 elements
    u16 hv[4][4], lv[4][4];
    #pragma unroll
    for (int i = 0; i < 4; ++i)
        #pragma unroll
        for (int j = 0; j < 4; ++j) splitf(acc[i][j], hv[i][j], lv[i][j]);

    const int e0t = eL0 + 4 * tc;
    const int hh  = e0t >> 7;
    const int d0  = e0t & 127;
    const int bhl = bgl * NH + hh;
    u16* hiB = ws + (size_t)(2 * which + 0) * nbh * EPB + (size_t)bhl * EPB;
    u16* loB = ws + (size_t)(2 * which + 1) * nbh * EPB + (size_t)bhl * EPB;

    if (which != 2) {
        // Q / K: per i (s-row), j contiguous in fragment (d-dim)
        const int kc = d0 >> 5, g = (d0 >> 3) & 3, j0 = d0 & 7;
        #pragma unroll
        for (int i = 0; i < 4; ++i) {
            const int s = sL0 + 4 * tr + i;
            size_t flat;
            if (which == 0) {
                const int q16 = s >> 4, c = s & 15;
                flat = ((size_t)(q16 * 4 + kc) * 64 + g * 16 + c) * 8 + j0;
            } else {
                const int T = s >> 5, nt = (s >> 4) & 1, c = s & 15;
                flat = ((size_t)((T * 4 + kc) * 2 + nt) * 64 + g * 16 + c) * 8 + j0;
            }
            us4 h4 = { hv[i][0], hv[i][1], hv[i][2], hv[i][3] };
            us4 l4 = { lv[i][0], lv[i][1], lv[i][2], lv[i][3] };
            *(us4*)(hiB + flat) = h4;
            *(us4*)(loB + flat) = l4;
        }
    } else {
        // V: per j (d-col), i contiguous in fragment (t-dim)
        const int s0 = sL0 + 4 * tr;
        const int T = s0 >> 5, gp = (s0 >> 3) & 3, jt0 = s0 & 7;
        #pragma unroll
        for (int j = 0; j < 4; ++j) {
            const int d = d0 + j;
            const int ni = d >> 4, cV = d & 15;
            size_t flat = ((size_t)(T * 8 + ni) * 64 + gp * 16 + cV) * 8 + jt0;
            us4 h4 = { hv[0][j], hv[1][j], hv[2][j], hv[3][j] };
            us4 l4 = { lv[0][j], lv[1][j], lv[2][j], lv[3][j] };
            *(us4*)(hiB + flat) = h4;
            *(us4*)(loB + flat) = l4;
        }
    }
}

// ---------------------------------------------------------------------------
// Attention: 4 waves x 32 q-rows = 128 q per block. Per K-tile(32):
// QK^T (split 3-MFMA), P->LDS bounce (C-layout -> A-layout), PV (split 3-MFMA).
// D-softmax in registers at the end, fp32 out.
// ---------------------------------------------------------------------------
#define MFMA(a, b, c) __builtin_amdgcn_mfma_f32_16x16x32_bf16((a), (b), (c), 0, 0, 0)

__global__ __launch_bounds__(256, 2) void attn_kernel(
    const u16* __restrict__ ws, float* __restrict__ outg, int b0, int nbh)
{
    __shared__ __align__(16) u16 sKH[4096];
    __shared__ __align__(16) u16 sKL[4096];
    __shared__ __align__(16) u16 sVH[4096];
    __shared__ __align__(16) u16 sVL[4096];
    __shared__ u32 sP[4][33 * 32];

    const int tid = threadIdx.x;
    const int Wv = tid >> 6;          // wave id
    const int l  = tid & 63;
    const int c  = l & 15;
    const int g  = l >> 4;
    const int bhl = blockIdx.y;
    const size_t tb = (size_t)bhl * EPB;
    const size_t TS = (size_t)nbh * EPB;

    const u16* QH = ws;
    const u16* QL = ws + TS;
    const u16* KH = ws + 2 * TS;
    const u16* KL = ws + 3 * TS;
    const u16* VH = ws + 4 * TS;
    const u16* VL = ws + 5 * TS;

    const int qb = blockIdx.x * 128 + Wv * 32;

    // hoist Q fragments (loop-invariant)
    bf16x8 qh[2][4], ql[2][4];
    #pragma unroll
    for (int mi = 0; mi < 2; ++mi)
        #pragma unroll
        for (int kc = 0; kc < 4; ++kc) {
            size_t f = tb + ((size_t)(((qb + 16 * mi) >> 4) * 4 + kc) * 64 + l) * 8;
            qh[mi][kc] = *(const bf16x8*)(QH + f);
            ql[mi][kc] = *(const bf16x8*)(QL + f);
        }

    f32x4 z[2][8];
    #pragma unroll
    for (int mi = 0; mi < 2; ++mi)
        #pragma unroll
        for (int ni = 0; ni < 8; ++ni) z[mi][ni] = (f32x4){0.f, 0.f, 0.f, 0.f};

    u32* sPW = &sP[Wv][0];
    const float scale = 0.08838834764831845f;   // 1/sqrt(128)

    for (int T = 0; T < 64; ++T) {
        const size_t off = tb + (size_t)T * 4096;
        const uint4* gKH = (const uint4*)(KH + off);
        const uint4* gKL = (const uint4*)(KL + off);
        const uint4* gVH = (const uint4*)(VH + off);
        const uint4* gVL = (const uint4*)(VL + off);
        uint4 r0 = gKH[tid], r1 = gKH[tid + 256];
        uint4 r2 = gKL[tid], r3 = gKL[tid + 256];
        uint4 r4 = gVH[tid], r5 = gVH[tid + 256];
        uint4 r6 = gVL[tid], r7 = gVL[tid + 256];
        __syncthreads();   // previous tile's compute done
        ((uint4*)sKH)[tid] = r0; ((uint4*)sKH)[tid + 256] = r1;
        ((uint4*)sKL)[tid] = r2; ((uint4*)sKL)[tid + 256] = r3;
        ((uint4*)sVH)[tid] = r4; ((uint4*)sVH)[tid + 256] = r5;
        ((uint4*)sVL)[tid] = r6; ((uint4*)sVL)[tid + 256] = r7;
        __syncthreads();   // staged

        // ---- QK^T: S[32q x 32t], split 3-MFMA over 4 k-chunks ----
        f32x4 s[2][2];
        #pragma unroll
        for (int mi = 0; mi < 2; ++mi)
            #pragma unroll
            for (int nt = 0; nt < 2; ++nt) s[mi][nt] = (f32x4){0.f, 0.f, 0.f, 0.f};
        #pragma unroll
        for (int kc = 0; kc < 4; ++kc) {
            bf16x8 kh0 = *(const bf16x8*)(sKH + ((kc * 2 + 0) * 64 + l) * 8);
            bf16x8 kh1 = *(const bf16x8*)(sKH + ((kc * 2 + 1) * 64 + l) * 8);
            bf16x8 kl0 = *(const bf16x8*)(sKL + ((kc * 2 + 0) * 64 + l) * 8);
            bf16x8 kl1 = *(const bf16x8*)(sKL + ((kc * 2 + 1) * 64 + l) * 8);
            #pragma unroll
            for (int mi = 0; mi < 2; ++mi) {
                s[mi][0] = MFMA(qh[mi][kc], kh0, s[mi][0]);
                s[mi][0] = MFMA(qh[mi][kc], kl0, s[mi][0]);
                s[mi][0] = MFMA(ql[mi][kc], kh0, s[mi][0]);
                s[mi][1] = MFMA(qh[mi][kc], kh1, s[mi][1]);
                s[mi][1] = MFMA(qh[mi][kc], kl1, s[mi][1]);
                s[mi][1] = MFMA(ql[mi][kc], kh1, s[mi][1]);
            }
        }

        // ---- P = scale*S -> bf16 hi/lo packed u32, C-layout -> LDS ----
        #pragma unroll
        for (int mi = 0; mi < 2; ++mi)
            #pragma unroll
            for (int nt = 0; nt < 2; ++nt)
                #pragma unroll
                for (int r = 0; r < 4; ++r) {
                    float p = s[mi][nt][r] * scale;
                    u16 ph, pl; splitf(p, ph, pl);
                    sPW[(nt * 16 + c) * 33 + mi * 16 + g * 4 + r] = (u32)ph | ((u32)pl << 16);
                }

        // ---- read P as A-fragments (wave-private, no barrier) ----
        bf16x8 pa_h[2], pa_l[2];
        #pragma unroll
        for (int mi = 0; mi < 2; ++mi)
            #pragma unroll
            for (int j = 0; j < 8; ++j) {
                u32 v = sPW[(8 * g + j) * 33 + mi * 16 + c];
                pa_h[mi][j] = (short)(v & 0xFFFFu);
                pa_l[mi][j] = (short)(v >> 16);
            }

        // ---- PV: Z += P @ V, split 3-MFMA ----
        #pragma unroll
        for (int ni = 0; ni < 8; ++ni) {
            bf16x8 vh = *(const bf16x8*)(sVH + (ni * 64 + l) * 8);
            bf16x8 vl = *(const bf16x8*)(sVL + (ni * 64 + l) * 8);
            #pragma unroll
            for (int mi = 0; mi < 2; ++mi) {
                z[mi][ni] = MFMA(pa_h[mi], vh, z[mi][ni]);
                z[mi][ni] = MFMA(pa_h[mi], vl, z[mi][ni]);
                z[mi][ni] = MFMA(pa_l[mi], vh, z[mi][ni]);
            }
        }
    }

    // ---- softmax over D=128 per q-row, fp32 store ----
    const size_t obase = (size_t)(b0 * NH + bhl) * EPB;
    #pragma unroll
    for (int mi = 0; mi < 2; ++mi)
        #pragma unroll
        for (int r = 0; r < 4; ++r) {
            float v[8];
            float m = -3.4e38f;
            #pragma unroll
            for (int ni = 0; ni < 8; ++ni) { v[ni] = z[mi][ni][r]; m = fmaxf(m, v[ni]); }
            #pragma unroll
            for (int off = 1; off < 16; off <<= 1) m = fmaxf(m, __shfl_xor(m, off, 64));
            float sum = 0.f;
            #pragma unroll
            for (int ni = 0; ni < 8; ++ni) { v[ni] = expf(v[ni] - m); sum += v[ni]; }
            #pragma unroll
            for (int off = 1; off < 16; off <<= 1) sum += __shfl_xor(sum, off, 64);
            const float inv = 1.f / sum;
            const int q = qb + 16 * mi + 4 * g + r;
            #pragma unroll
            for (int ni = 0; ni < 8; ++ni)
                outg[obase + (size_t)q * ND + ni * 16 + c] = v[ni] * inv;
        }
}

extern "C" void kernel_launch(void* const* d_in, const int* in_sizes, int n_in,
                              void* d_out, int out_size, void* d_ws, size_t ws_size,
                              hipStream_t stream)
{
    (void)out_size;
    int xi = 0;
    for (int i = 0; i < n_in && i < 4; ++i)
        if (in_sizes[i] == NB * NS * ND) { xi = i; break; }
    const float* x = (const float*)d_in[xi];
    const float* Wsp[3]; int w = 0;
    for (int i = 0; i < 4; ++i) if (i != xi) Wsp[w++] = (const float*)d_in[i];
    const float* Wq = Wsp[0];
    const float* Wk = Wsp[1];
    const float* Wv = Wsp[2];
    float* out = (float*)d_out;
    u16* ws = (u16*)d_ws;

    // ws per slice of nb batches: 6 tensors x nb*NH*EPB bf16
    auto slice_bytes = [](int nb) { return (size_t)6 * nb * NH * EPB * 2; };
    int nb = (ws_size >= slice_bytes(4)) ? 4 : (ws_size >= slice_bytes(2)) ? 2 : 1;
    const int nbh = nb * NH;

    for (int b0 = 0; b0 < NB; b0 += nb) {
        proj_kernel<<<dim3(nb * 32, 16, 3), dim3(256), 0, stream>>>(
            x, Wq, Wk, Wv, ws, b0, nbh);
        attn_kernel<<<dim3(16, nbh), dim3(256), 0, stream>>>(
            ws, out, b0, nbh);
    }
}

// Round 8
// 347.773 us; speedup vs baseline: 5.3529x; 1.0059x over previous
//
#include <hip/hip_runtime.h>
#include <hip/hip_bf16.h>

// MHA, softmax over model-dim AFTER A@V => plain accumulation, no online softmax.
// Round 8: round-6's VERIFIED bf16 3-MFMA numerics (passed at 3.9e-3 floor) on
// round-7's VERIFIED staging structure (global_load_lds dbuf + counted vmcnt +
// raw barriers + setprio; round-7's 0.047 fail was numerics-only — fp16 2-MFMA
// dropped-term error, structure proven correct by the small structured error).
// LDS: 4 staged tensors (KH/KL/VH/VL) x dbuf = 64KB + per-mi P bounce 8.7KB
// = 74.2KB -> 2 blocks/CU kept. Q hi/lo in regs; P hi/lo transient.

#define NB 4
#define NS 2048
#define ND 128
#define NH 8
#define EPB (NS * ND)   // 262144 elems per (b,h)

typedef unsigned short u16;
typedef unsigned int u32;
typedef short bf16x8 __attribute__((ext_vector_type(8)));
typedef float f32x4 __attribute__((ext_vector_type(4)));

struct __align__(8) us4 { u16 a, b, c, d; };

#define MFMA(a, b, c) __builtin_amdgcn_mfma_f32_16x16x32_bf16((a), (b), (c), 0, 0, 0)

__device__ __forceinline__ void splitf(float f, u16& hi, u16& lo) {
    u32 fb = __float_as_uint(f);
    u32 hb = fb + 0x7FFFu + ((fb >> 16) & 1u);      // RNE to bf16
    hi = (u16)(hb >> 16);
    float fh = __uint_as_float((hb >> 16) << 16);
    float fl = f - fh;                               // exact residual
    u32 lb = __float_as_uint(fl);
    u32 lr = lb + 0x7FFFu + ((lb >> 16) & 1u);
    lo = (u16)(lr >> 16);
}

// ws layout (bf16 u16): 0=QH 1=QL 2=KH 3=KL 4=VH 5=VL, each [bhl][frag-ordered EPB]

// ---------------------------------------------------------------------------
// Projection: fp32 VALU GEMM (verified) with reg-prefetched kk=1 stage;
// epilogue splits acc to bf16 hi/lo into MFMA-fragment-ordered ws.
// ---------------------------------------------------------------------------
__global__ __launch_bounds__(256) void proj_kernel(
    const float* __restrict__ xg, const float* __restrict__ Wqg,
    const float* __restrict__ Wkg, const float* __restrict__ Wvg,
    u16* __restrict__ ws, int b0, int nbh)
{
    __shared__ float xsT[64][68];
    __shared__ float wsT[64][68];

    const int which = blockIdx.z;
    const float* __restrict__ W = (which == 0) ? Wqg : (which == 1) ? Wkg : Wvg;

    const int tid = threadIdx.x;
    const int bgl = blockIdx.x >> 5;
    const int sL0 = (blockIdx.x & 31) * 64;
    const int eL0 = blockIdx.y * 64;
    const int mG0 = (b0 + bgl) * NS + sL0;
    const int tr = tid >> 4;
    const int tc = tid & 15;

    const int fr = tid & 63;          // stage row
    const int fk = tid >> 6;          // stage k-group base

    float4 xv[4], wv[4];
    #pragma unroll
    for (int i = 0; i < 4; ++i) {
        xv[i] = *(const float4*)&xg[(size_t)(mG0 + fr) * ND + (fk + i * 4) * 4];
        wv[i] = *(const float4*)&W[(size_t)(eL0 + fr) * ND + (fk + i * 4) * 4];
    }

    float acc[4][4];
    #pragma unroll
    for (int i = 0; i < 4; ++i)
        #pragma unroll
        for (int j = 0; j < 4; ++j) acc[i][j] = 0.f;

    for (int kk = 0; kk < 2; ++kk) {
        __syncthreads();
        #pragma unroll
        for (int i = 0; i < 4; ++i) {
            int kg = fk + i * 4;
            xsT[kg * 4 + 0][fr] = xv[i].x;
            xsT[kg * 4 + 1][fr] = xv[i].y;
            xsT[kg * 4 + 2][fr] = xv[i].z;
            xsT[kg * 4 + 3][fr] = xv[i].w;
            wsT[kg * 4 + 0][fr] = wv[i].x;
            wsT[kg * 4 + 1][fr] = wv[i].y;
            wsT[kg * 4 + 2][fr] = wv[i].z;
            wsT[kg * 4 + 3][fr] = wv[i].w;
        }
        __syncthreads();
        if (kk == 0) {
            #pragma unroll
            for (int i = 0; i < 4; ++i) {
                xv[i] = *(const float4*)&xg[(size_t)(mG0 + fr) * ND + 64 + (fk + i * 4) * 4];
                wv[i] = *(const float4*)&W[(size_t)(eL0 + fr) * ND + 64 + (fk + i * 4) * 4];
            }
        }
        #pragma unroll 4
        for (int k = 0; k < 64; ++k) {
            const float4 a = *(const float4*)&xsT[k][tr * 4];
            const float4 b = *(const float4*)&wsT[k][tc * 4];
            acc[0][0] += a.x * b.x; acc[0][1] += a.x * b.y; acc[0][2] += a.x * b.z; acc[0][3] += a.x * b.w;
            acc[1][0] += a.y * b.x; acc[1][1] += a.y * b.y; acc[1][2] += a.y * b.z; acc[1][3] += a.y * b.w;
            acc[2][0] += a.z * b.x; acc[2][1] += a.z * b.y; acc[2][2] += a.z * b.z; acc[2][3] += a.z * b.w;
            acc[3][0] += a.w * b.x; acc[3][1] += a.w * b.y; acc[3][2] += a.w * b.z; acc[3][3] += a.w * b.w;
        }
    }

    // split all 16 elements to bf16 hi/lo
    u16 hv[4][4], lv[4][4];
    #pragma unroll
    for (int i = 0; i < 4; ++i)
        #pragma unroll
        for (int j = 0; j < 4; ++j) splitf(acc[i][j], hv[i][j], lv[i][j]);

    const int e0t = eL0 + 4 * tc;
    const int hh  = e0t >> 7;
    const int d0  = e0t & 127;
    const int bhl = bgl * NH + hh;
    const size_t TS = (size_t)nbh * EPB;
    const size_t tb = (size_t)bhl * EPB;

    if (which == 0) {
        u16* HB = ws + 0 * TS + tb;
        u16* LB = ws + 1 * TS + tb;
        const int kc = d0 >> 5, g = (d0 >> 3) & 3, j0 = d0 & 7;
        #pragma unroll
        for (int i = 0; i < 4; ++i) {
            const int s = sL0 + 4 * tr + i;
            const int q16 = s >> 4, c = s & 15;
            size_t flat = ((size_t)(q16 * 4 + kc) * 64 + g * 16 + c) * 8 + j0;
            us4 h4 = { hv[i][0], hv[i][1], hv[i][2], hv[i][3] };
            us4 l4 = { lv[i][0], lv[i][1], lv[i][2], lv[i][3] };
            *(us4*)(HB + flat) = h4;
            *(us4*)(LB + flat) = l4;
        }
    } else if (which == 1) {
        u16* HB = ws + 2 * TS + tb;
        u16* LB = ws + 3 * TS + tb;
        const int kc = d0 >> 5, g = (d0 >> 3) & 3, j0 = d0 & 7;
        #pragma unroll
        for (int i = 0; i < 4; ++i) {
            const int s = sL0 + 4 * tr + i;
            const int T = s >> 5, nt = (s >> 4) & 1, c = s & 15;
            size_t flat = ((size_t)((T * 4 + kc) * 2 + nt) * 64 + g * 16 + c) * 8 + j0;
            us4 h4 = { hv[i][0], hv[i][1], hv[i][2], hv[i][3] };
            us4 l4 = { lv[i][0], lv[i][1], lv[i][2], lv[i][3] };
            *(us4*)(HB + flat) = h4;
            *(us4*)(LB + flat) = l4;
        }
    } else {
        u16* HB = ws + 4 * TS + tb;
        u16* LB = ws + 5 * TS + tb;
        const int s0 = sL0 + 4 * tr;
        const int T = s0 >> 5, gp = (s0 >> 3) & 3, jt0 = s0 & 7;
        #pragma unroll
        for (int j = 0; j < 4; ++j) {
            const int d = d0 + j;
            const int ni = d >> 4, cV = d & 15;
            size_t flat = ((size_t)(T * 8 + ni) * 64 + gp * 16 + cV) * 8 + jt0;
            us4 h4 = { hv[0][j], hv[1][j], hv[2][j], hv[3][j] };
            us4 l4 = { lv[0][j], lv[1][j], lv[2][j], lv[3][j] };
            *(us4*)(HB + flat) = h4;
            *(us4*)(LB + flat) = l4;
        }
    }
}

// ---------------------------------------------------------------------------
// Attention: 4 waves x 32 q. Per 32-t tile: QK^T (bf16 3-MFMA), per-mi P
// hi/lo bounce, PV (bf16 3-MFMA). K/V via global_load_lds dbuf, vmcnt(8).
// ---------------------------------------------------------------------------
__global__ __launch_bounds__(256, 2) void attn_kernel(
    const u16* __restrict__ ws, float* __restrict__ outg, int b0, int nbh)
{
    __shared__ __align__(16) u16 sbuf[2][4][4096];   // [dbuf][KH,KL,VH,VL][32t x 128d]
    __shared__ u32 sP[4][32 * 17];                   // per-wave per-mi P bounce

    const int tid = threadIdx.x;
    const int Wv = tid >> 6;
    const int l  = tid & 63;
    const int c  = l & 15;
    const int g  = l >> 4;
    const int bhl = blockIdx.y;
    const size_t tb = (size_t)bhl * EPB;
    const size_t TS = (size_t)nbh * EPB;

    const u16* QH = ws;
    const u16* QL = ws + 1 * TS;
    const u16* KH = ws + 2 * TS;
    const u16* KL = ws + 3 * TS;
    const u16* VH = ws + 4 * TS;
    const u16* VL = ws + 5 * TS;

    const int qb = blockIdx.x * 128 + Wv * 32;

    // Q fragments hi/lo (loop-invariant, registers)
    bf16x8 qh[2][4], ql[2][4];
    #pragma unroll
    for (int mi = 0; mi < 2; ++mi)
        #pragma unroll
        for (int kc = 0; kc < 4; ++kc) {
            size_t f = tb + ((size_t)(((qb + 16 * mi) >> 4) * 4 + kc) * 64 + l) * 8;
            qh[mi][kc] = *(const bf16x8*)(QH + f);
            ql[mi][kc] = *(const bf16x8*)(QL + f);
        }

    f32x4 z[2][8];
    #pragma unroll
    for (int mi = 0; mi < 2; ++mi)
        #pragma unroll
        for (int ni = 0; ni < 8; ++ni) z[mi][ni] = (f32x4){0.f, 0.f, 0.f, 0.f};

    const u16* srcs[4] = { KH, KL, VH, VL };
    auto stage = [&](int buf, int T) {
        #pragma unroll
        for (int t4 = 0; t4 < 4; ++t4)
            #pragma unroll
            for (int r = 0; r < 2; ++r)
                __builtin_amdgcn_global_load_lds(
                    (const __attribute__((address_space(1))) void*)
                        (srcs[t4] + tb + (size_t)T * 4096 + r * 2048 + tid * 8),
                    (__attribute__((address_space(3))) void*)
                        (&sbuf[buf][t4][r * 2048 + tid * 8]),
                    16, 0, 0);
    };

    u32* sPW = &sP[Wv][0];
    const float scale = 0.08838834764831845f;   // 1/sqrt(128)

    stage(0, 0);

    for (int T = 0; T < 64; ++T) {
        const int cur = T & 1;
        if (T < 63) {
            stage(cur ^ 1, T + 1);
            asm volatile("s_waitcnt vmcnt(8)" ::: "memory");   // cur tile landed
        } else {
            asm volatile("s_waitcnt vmcnt(0)" ::: "memory");
        }
        __builtin_amdgcn_s_barrier();
        asm volatile("" ::: "memory");

        const u16* bKH = &sbuf[cur][0][0];
        const u16* bKL = &sbuf[cur][1][0];
        const u16* bVH = &sbuf[cur][2][0];
        const u16* bVL = &sbuf[cur][3][0];

        // ---- QK^T: S = Qh*Kh + Qh*Kl + Ql*Kh (48 MFMAs) ----
        f32x4 s[2][2];
        #pragma unroll
        for (int mi = 0; mi < 2; ++mi)
            #pragma unroll
            for (int nt = 0; nt < 2; ++nt) s[mi][nt] = (f32x4){0.f, 0.f, 0.f, 0.f};
        __builtin_amdgcn_s_setprio(1);
        #pragma unroll
        for (int kc = 0; kc < 4; ++kc) {
            bf16x8 kh0 = *(const bf16x8*)(bKH + ((kc * 2 + 0) * 64 + l) * 8);
            bf16x8 kh1 = *(const bf16x8*)(bKH + ((kc * 2 + 1) * 64 + l) * 8);
            bf16x8 kl0 = *(const bf16x8*)(bKL + ((kc * 2 + 0) * 64 + l) * 8);
            bf16x8 kl1 = *(const bf16x8*)(bKL + ((kc * 2 + 1) * 64 + l) * 8);
            #pragma unroll
            for (int mi = 0; mi < 2; ++mi) {
                s[mi][0] = MFMA(qh[mi][kc], kh0, s[mi][0]);
                s[mi][0] = MFMA(qh[mi][kc], kl0, s[mi][0]);
                s[mi][0] = MFMA(ql[mi][kc], kh0, s[mi][0]);
                s[mi][1] = MFMA(qh[mi][kc], kh1, s[mi][1]);
                s[mi][1] = MFMA(qh[mi][kc], kl1, s[mi][1]);
                s[mi][1] = MFMA(ql[mi][kc], kh1, s[mi][1]);
            }
        }
        __builtin_amdgcn_s_setprio(0);

        // ---- per-mi P bounce: C-layout -> A-layout, bf16 hi/lo packed ----
        bf16x8 pa_h[2], pa_l[2];
        #pragma unroll
        for (int mi = 0; mi < 2; ++mi) {
            #pragma unroll
            for (int nt = 0; nt < 2; ++nt)
                #pragma unroll
                for (int r = 0; r < 4; ++r) {
                    float p = s[mi][nt][r] * scale;
                    u16 ph, pl; splitf(p, ph, pl);
                    sPW[(nt * 16 + c) * 17 + 4 * g + r] = (u32)ph | ((u32)pl << 16);
                }
            union { u16 uh[8]; bf16x8 v; } ph8;
            union { u16 ul[8]; bf16x8 v; } pl8;
            #pragma unroll
            for (int j = 0; j < 8; ++j) {
                u32 v = sPW[(8 * g + j) * 17 + c];
                ph8.uh[j] = (u16)(v & 0xFFFFu);
                pl8.ul[j] = (u16)(v >> 16);
            }
            pa_h[mi] = ph8.v;
            pa_l[mi] = pl8.v;
        }

        // ---- PV: Z += Ph*Vh + Ph*Vl + Pl*Vh (48 MFMAs) ----
        __builtin_amdgcn_s_setprio(1);
        #pragma unroll
        for (int ni = 0; ni < 8; ++ni) {
            bf16x8 vh = *(const bf16x8*)(bVH + (ni * 64 + l) * 8);
            bf16x8 vl = *(const bf16x8*)(bVL + (ni * 64 + l) * 8);
            #pragma unroll
            for (int mi = 0; mi < 2; ++mi) {
                z[mi][ni] = MFMA(pa_h[mi], vh, z[mi][ni]);
                z[mi][ni] = MFMA(pa_h[mi], vl, z[mi][ni]);
                z[mi][ni] = MFMA(pa_l[mi], vh, z[mi][ni]);
            }
        }
        __builtin_amdgcn_s_setprio(0);

        asm volatile("" ::: "memory");
        __builtin_amdgcn_s_barrier();   // all waves done with buf[cur] before restage
    }

    // ---- softmax over D=128 per q-row, fp32 store ----
    const size_t obase = (size_t)(b0 * NH + bhl) * EPB;
    #pragma unroll
    for (int mi = 0; mi < 2; ++mi)
        #pragma unroll
        for (int r = 0; r < 4; ++r) {
            float v[8];
            float m = -3.4e38f;
            #pragma unroll
            for (int ni = 0; ni < 8; ++ni) { v[ni] = z[mi][ni][r]; m = fmaxf(m, v[ni]); }
            #pragma unroll
            for (int off = 1; off < 16; off <<= 1) m = fmaxf(m, __shfl_xor(m, off, 64));
            float sum = 0.f;
            #pragma unroll
            for (int ni = 0; ni < 8; ++ni) { v[ni] = expf(v[ni] - m); sum += v[ni]; }
            #pragma unroll
            for (int off = 1; off < 16; off <<= 1) sum += __shfl_xor(sum, off, 64);
            const float inv = 1.f / sum;
            const int q = qb + 16 * mi + 4 * g + r;
            #pragma unroll
            for (int ni = 0; ni < 8; ++ni)
                outg[obase + (size_t)q * ND + ni * 16 + c] = v[ni] * inv;
        }
}

extern "C" void kernel_launch(void* const* d_in, const int* in_sizes, int n_in,
                              void* d_out, int out_size, void* d_ws, size_t ws_size,
                              hipStream_t stream)
{
    (void)out_size;
    int xi = 0;
    for (int i = 0; i < n_in && i < 4; ++i)
        if (in_sizes[i] == NB * NS * ND) { xi = i; break; }
    const float* x = (const float*)d_in[xi];
    const float* Wsp[3]; int w = 0;
    for (int i = 0; i < 4; ++i) if (i != xi) Wsp[w++] = (const float*)d_in[i];
    const float* Wq = Wsp[0];
    const float* Wk = Wsp[1];
    const float* Wv = Wsp[2];
    float* out = (float*)d_out;
    u16* ws = (u16*)d_ws;

    // 6 bf16 tensors per slice of nb batches
    auto slice_bytes = [](int nb) { return (size_t)6 * nb * NH * EPB * 2; };
    int nb = (ws_size >= slice_bytes(4)) ? 4 : (ws_size >= slice_bytes(2)) ? 2 : 1;
    const int nbh = nb * NH;

    for (int b0 = 0; b0 < NB; b0 += nb) {
        proj_kernel<<<dim3(nb * 32, 16, 3), dim3(256), 0, stream>>>(
            x, Wq, Wk, Wv, ws, b0, nbh);
        attn_kernel<<<dim3(16, nbh), dim3(256), 0, stream>>>(
            ws, out, b0, nbh);
    }
}

// Round 9
// 332.390 us; speedup vs baseline: 5.6006x; 1.0463x over previous
//
#include <hip/hip_runtime.h>
#include <hip/hip_bf16.h>

// MHA, softmax over model-dim AFTER A@V => plain accumulation, no online softmax.
// Round 9: MFMA-ize the projection (3-term bf16 hi/lo split GEMM, zero LDS,
// frags straight from global with inline split; epilogue writes the SAME
// fragment-ordered ws bits as round 8). Attention kernel byte-identical to
// round 8 (verified: pass @ 3.9e-3 floor, 215us, MfmaUtil 44%).
// Model (corrected units): 16x16x32 MFMA ~16 cyc/SIMD at 2.5PF peak.
// attn MFMA floor 82us (206 GF split work); proj MFMA floor 7.7us (19.3 GF)
// vs 133us measured fp32-VALU -> proj is the mispriced item this round.

#define NB 4
#define NS 2048
#define ND 128
#define NH 8
#define EPB (NS * ND)   // 262144 elems per (b,h)

typedef unsigned short u16;
typedef unsigned int u32;
typedef short bf16x8 __attribute__((ext_vector_type(8)));
typedef float f32x4 __attribute__((ext_vector_type(4)));

#define MFMA(a, b, c) __builtin_amdgcn_mfma_f32_16x16x32_bf16((a), (b), (c), 0, 0, 0)

__device__ __forceinline__ void splitf(float f, u16& hi, u16& lo) {
    u32 fb = __float_as_uint(f);
    u32 hb = fb + 0x7FFFu + ((fb >> 16) & 1u);      // RNE to bf16
    hi = (u16)(hb >> 16);
    float fh = __uint_as_float((hb >> 16) << 16);
    float fl = f - fh;                               // exact residual
    u32 lb = __float_as_uint(fl);
    u32 lr = lb + 0x7FFFu + ((lb >> 16) & 1u);
    lo = (u16)(lr >> 16);
}

// ws layout (bf16 u16): 0=QH 1=QL 2=KH 3=KL 4=VH 5=VL, each [bhl][frag-ordered EPB]

// ---------------------------------------------------------------------------
// Projection, MFMA version. Block 256 = 4 waves (2s x 2e), tile 64s x 128e.
// Wave tile 32s x 64e = 2mi x 4ni accs. K=128 = 4 kc chunks, 3-term split:
// y = xh*wh + xh*wl + xl*wh (dropped xl*wl ~2^-18 rel). No LDS, no barriers.
// A-frag read: lane l: row s = base + (l&15), d = kc*32 + (l>>4)*8 + j  (x2 float4)
// B-frag read: lane l: col e = base + (l&15), d likewise.  (verified layout:
// same mapping attn's QK uses, hardware-proven by round-8 pass.)
// ---------------------------------------------------------------------------
__global__ __launch_bounds__(256) void proj_kernel(
    const float* __restrict__ xg, const float* __restrict__ Wqg,
    const float* __restrict__ Wkg, const float* __restrict__ Wvg,
    u16* __restrict__ ws, int b0, int nbh)
{
    const int which = blockIdx.z;
    const float* __restrict__ Wt = (which == 0) ? Wqg : (which == 1) ? Wkg : Wvg;

    const int tid = threadIdx.x;
    const int wv = tid >> 6;
    const int l  = tid & 63;
    const int c  = l & 15;
    const int g  = l >> 4;
    const int wr = wv & 1;
    const int wc = wv >> 1;
    const int s0 = b0 * NS + blockIdx.x * 64 + wr * 32;   // global x row
    const int e0 = blockIdx.y * 128 + wc * 64;            // W row (= h*128+d)

    f32x4 acc[2][4];
    #pragma unroll
    for (int mi = 0; mi < 2; ++mi)
        #pragma unroll
        for (int ni = 0; ni < 4; ++ni) acc[mi][ni] = (f32x4){0.f, 0.f, 0.f, 0.f};

    #pragma unroll
    for (int kc = 0; kc < 4; ++kc) {
        bf16x8 ah[2], al[2], bh[4], bl[4];
        #pragma unroll
        for (int mi = 0; mi < 2; ++mi) {
            const float* p = xg + (size_t)(s0 + mi * 16 + c) * ND + kc * 32 + g * 8;
            float4 v0 = *(const float4*)p;
            float4 v1 = *(const float4*)(p + 4);
            union { u16 u[8]; bf16x8 v; } H, L;
            float vv[8] = { v0.x, v0.y, v0.z, v0.w, v1.x, v1.y, v1.z, v1.w };
            #pragma unroll
            for (int j = 0; j < 8; ++j) splitf(vv[j], H.u[j], L.u[j]);
            ah[mi] = H.v; al[mi] = L.v;
        }
        #pragma unroll
        for (int ni = 0; ni < 4; ++ni) {
            const float* p = Wt + (size_t)(e0 + ni * 16 + c) * ND + kc * 32 + g * 8;
            float4 v0 = *(const float4*)p;
            float4 v1 = *(const float4*)(p + 4);
            union { u16 u[8]; bf16x8 v; } H, L;
            float vv[8] = { v0.x, v0.y, v0.z, v0.w, v1.x, v1.y, v1.z, v1.w };
            #pragma unroll
            for (int j = 0; j < 8; ++j) splitf(vv[j], H.u[j], L.u[j]);
            bh[ni] = H.v; bl[ni] = L.v;
        }
        #pragma unroll
        for (int mi = 0; mi < 2; ++mi)
            #pragma unroll
            for (int ni = 0; ni < 4; ++ni) {
                acc[mi][ni] = MFMA(ah[mi], bh[ni], acc[mi][ni]);
                acc[mi][ni] = MFMA(ah[mi], bl[ni], acc[mi][ni]);
                acc[mi][ni] = MFMA(al[mi], bh[ni], acc[mi][ni]);
            }
    }

    // epilogue: split acc to bf16 hi/lo, scatter into round-8 frag orderings.
    // C-layout: lane holds col e = e0+ni*16+c, rows s = s0+mi*16+4g+r.
    const size_t TS = (size_t)nbh * EPB;
    #pragma unroll
    for (int mi = 0; mi < 2; ++mi)
        #pragma unroll
        for (int ni = 0; ni < 4; ++ni)
            #pragma unroll
            for (int r = 0; r < 4; ++r) {
                const int sg = s0 + mi * 16 + 4 * g + r;
                const int e  = e0 + ni * 16 + c;
                const int bl_ = (sg >> 11) - b0;
                const int sl  = sg & 2047;
                const int h = e >> 7, d = e & 127;
                const size_t tb = (size_t)(bl_ * NH + h) * EPB;
                u16 ph, pl;
                splitf(acc[mi][ni][r], ph, pl);
                size_t flat;
                if (which == 0) {
                    flat = ((size_t)((sl >> 4) * 4 + (d >> 5)) * 64
                            + ((d >> 3) & 3) * 16 + (sl & 15)) * 8 + (d & 7);
                    ws[0 * TS + tb + flat] = ph;
                    ws[1 * TS + tb + flat] = pl;
                } else if (which == 1) {
                    flat = ((size_t)(((sl >> 5) * 4 + (d >> 5)) * 2 + ((sl >> 4) & 1)) * 64
                            + ((d >> 3) & 3) * 16 + (sl & 15)) * 8 + (d & 7);
                    ws[2 * TS + tb + flat] = ph;
                    ws[3 * TS + tb + flat] = pl;
                } else {
                    flat = ((size_t)((sl >> 5) * 8 + (d >> 4)) * 64
                            + ((sl >> 3) & 3) * 16 + (d & 15)) * 8 + (sl & 7);
                    ws[4 * TS + tb + flat] = ph;
                    ws[5 * TS + tb + flat] = pl;
                }
            }
}

// ---------------------------------------------------------------------------
// Attention: byte-identical to round 8 (verified).
// ---------------------------------------------------------------------------
__global__ __launch_bounds__(256, 2) void attn_kernel(
    const u16* __restrict__ ws, float* __restrict__ outg, int b0, int nbh)
{
    __shared__ __align__(16) u16 sbuf[2][4][4096];   // [dbuf][KH,KL,VH,VL][32t x 128d]
    __shared__ u32 sP[4][32 * 17];                   // per-wave per-mi P bounce

    const int tid = threadIdx.x;
    const int Wv = tid >> 6;
    const int l  = tid & 63;
    const int c  = l & 15;
    const int g  = l >> 4;
    const int bhl = blockIdx.y;
    const size_t tb = (size_t)bhl * EPB;
    const size_t TS = (size_t)nbh * EPB;

    const u16* QH = ws;
    const u16* QL = ws + 1 * TS;
    const u16* KH = ws + 2 * TS;
    const u16* KL = ws + 3 * TS;
    const u16* VH = ws + 4 * TS;
    const u16* VL = ws + 5 * TS;

    const int qb = blockIdx.x * 128 + Wv * 32;

    // Q fragments hi/lo (loop-invariant, registers)
    bf16x8 qh[2][4], ql[2][4];
    #pragma unroll
    for (int mi = 0; mi < 2; ++mi)
        #pragma unroll
        for (int kc = 0; kc < 4; ++kc) {
            size_t f = tb + ((size_t)(((qb + 16 * mi) >> 4) * 4 + kc) * 64 + l) * 8;
            qh[mi][kc] = *(const bf16x8*)(QH + f);
            ql[mi][kc] = *(const bf16x8*)(QL + f);
        }

    f32x4 z[2][8];
    #pragma unroll
    for (int mi = 0; mi < 2; ++mi)
        #pragma unroll
        for (int ni = 0; ni < 8; ++ni) z[mi][ni] = (f32x4){0.f, 0.f, 0.f, 0.f};

    const u16* srcs[4] = { KH, KL, VH, VL };
    auto stage = [&](int buf, int T) {
        #pragma unroll
        for (int t4 = 0; t4 < 4; ++t4)
            #pragma unroll
            for (int r = 0; r < 2; ++r)
                __builtin_amdgcn_global_load_lds(
                    (const __attribute__((address_space(1))) void*)
                        (srcs[t4] + tb + (size_t)T * 4096 + r * 2048 + tid * 8),
                    (__attribute__((address_space(3))) void*)
                        (&sbuf[buf][t4][r * 2048 + tid * 8]),
                    16, 0, 0);
    };

    u32* sPW = &sP[Wv][0];
    const float scale = 0.08838834764831845f;   // 1/sqrt(128)

    stage(0, 0);

    for (int T = 0; T < 64; ++T) {
        const int cur = T & 1;
        if (T < 63) {
            stage(cur ^ 1, T + 1);
            asm volatile("s_waitcnt vmcnt(8)" ::: "memory");   // cur tile landed
        } else {
            asm volatile("s_waitcnt vmcnt(0)" ::: "memory");
        }
        __builtin_amdgcn_s_barrier();
        asm volatile("" ::: "memory");

        const u16* bKH = &sbuf[cur][0][0];
        const u16* bKL = &sbuf[cur][1][0];
        const u16* bVH = &sbuf[cur][2][0];
        const u16* bVL = &sbuf[cur][3][0];

        // ---- QK^T: S = Qh*Kh + Qh*Kl + Ql*Kh (48 MFMAs) ----
        f32x4 s[2][2];
        #pragma unroll
        for (int mi = 0; mi < 2; ++mi)
            #pragma unroll
            for (int nt = 0; nt < 2; ++nt) s[mi][nt] = (f32x4){0.f, 0.f, 0.f, 0.f};
        __builtin_amdgcn_s_setprio(1);
        #pragma unroll
        for (int kc = 0; kc < 4; ++kc) {
            bf16x8 kh0 = *(const bf16x8*)(bKH + ((kc * 2 + 0) * 64 + l) * 8);
            bf16x8 kh1 = *(const bf16x8*)(bKH + ((kc * 2 + 1) * 64 + l) * 8);
            bf16x8 kl0 = *(const bf16x8*)(bKL + ((kc * 2 + 0) * 64 + l) * 8);
            bf16x8 kl1 = *(const bf16x8*)(bKL + ((kc * 2 + 1) * 64 + l) * 8);
            #pragma unroll
            for (int mi = 0; mi < 2; ++mi) {
                s[mi][0] = MFMA(qh[mi][kc], kh0, s[mi][0]);
                s[mi][0] = MFMA(qh[mi][kc], kl0, s[mi][0]);
                s[mi][0] = MFMA(ql[mi][kc], kh0, s[mi][0]);
                s[mi][1] = MFMA(qh[mi][kc], kh1, s[mi][1]);
                s[mi][1] = MFMA(qh[mi][kc], kl1, s[mi][1]);
                s[mi][1] = MFMA(ql[mi][kc], kh1, s[mi][1]);
            }
        }
        __builtin_amdgcn_s_setprio(0);

        // ---- per-mi P bounce: C-layout -> A-layout, bf16 hi/lo packed ----
        bf16x8 pa_h[2], pa_l[2];
        #pragma unroll
        for (int mi = 0; mi < 2; ++mi) {
            #pragma unroll
            for (int nt = 0; nt < 2; ++nt)
                #pragma unroll
                for (int r = 0; r < 4; ++r) {
                    float p = s[mi][nt][r] * scale;
                    u16 ph, pl; splitf(p, ph, pl);
                    sPW[(nt * 16 + c) * 17 + 4 * g + r] = (u32)ph | ((u32)pl << 16);
                }
            union { u16 uh[8]; bf16x8 v; } ph8;
            union { u16 ul[8]; bf16x8 v; } pl8;
            #pragma unroll
            for (int j = 0; j < 8; ++j) {
                u32 v = sPW[(8 * g + j) * 17 + c];
                ph8.uh[j] = (u16)(v & 0xFFFFu);
                pl8.ul[j] = (u16)(v >> 16);
            }
            pa_h[mi] = ph8.v;
            pa_l[mi] = pl8.v;
        }

        // ---- PV: Z += Ph*Vh + Ph*Vl + Pl*Vh (48 MFMAs) ----
        __builtin_amdgcn_s_setprio(1);
        #pragma unroll
        for (int ni = 0; ni < 8; ++ni) {
            bf16x8 vh = *(const bf16x8*)(bVH + (ni * 64 + l) * 8);
            bf16x8 vl = *(const bf16x8*)(bVL + (ni * 64 + l) * 8);
            #pragma unroll
            for (int mi = 0; mi < 2; ++mi) {
                z[mi][ni] = MFMA(pa_h[mi], vh, z[mi][ni]);
                z[mi][ni] = MFMA(pa_h[mi], vl, z[mi][ni]);
                z[mi][ni] = MFMA(pa_l[mi], vh, z[mi][ni]);
            }
        }
        __builtin_amdgcn_s_setprio(0);

        asm volatile("" ::: "memory");
        __builtin_amdgcn_s_barrier();   // all waves done with buf[cur] before restage
    }

    // ---- softmax over D=128 per q-row, fp32 store ----
    const size_t obase = (size_t)(b0 * NH + bhl) * EPB;
    #pragma unroll
    for (int mi = 0; mi < 2; ++mi)
        #pragma unroll
        for (int r = 0; r < 4; ++r) {
            float v[8];
            float m = -3.4e38f;
            #pragma unroll
            for (int ni = 0; ni < 8; ++ni) { v[ni] = z[mi][ni][r]; m = fmaxf(m, v[ni]); }
            #pragma unroll
            for (int off = 1; off < 16; off <<= 1) m = fmaxf(m, __shfl_xor(m, off, 64));
            float sum = 0.f;
            #pragma unroll
            for (int ni = 0; ni < 8; ++ni) { v[ni] = expf(v[ni] - m); sum += v[ni]; }
            #pragma unroll
            for (int off = 1; off < 16; off <<= 1) sum += __shfl_xor(sum, off, 64);
            const float inv = 1.f / sum;
            const int q = qb + 16 * mi + 4 * g + r;
            #pragma unroll
            for (int ni = 0; ni < 8; ++ni)
                outg[obase + (size_t)q * ND + ni * 16 + c] = v[ni] * inv;
        }
}

extern "C" void kernel_launch(void* const* d_in, const int* in_sizes, int n_in,
                              void* d_out, int out_size, void* d_ws, size_t ws_size,
                              hipStream_t stream)
{
    (void)out_size;
    int xi = 0;
    for (int i = 0; i < n_in && i < 4; ++i)
        if (in_sizes[i] == NB * NS * ND) { xi = i; break; }
    const float* x = (const float*)d_in[xi];
    const float* Wsp[3]; int w = 0;
    for (int i = 0; i < 4; ++i) if (i != xi) Wsp[w++] = (const float*)d_in[i];
    const float* Wq = Wsp[0];
    const float* Wk = Wsp[1];
    const float* Wv = Wsp[2];
    float* out = (float*)d_out;
    u16* ws = (u16*)d_ws;

    // 6 bf16 tensors per slice of nb batches
    auto slice_bytes = [](int nb) { return (size_t)6 * nb * NH * EPB * 2; };
    int nb = (ws_size >= slice_bytes(4)) ? 4 : (ws_size >= slice_bytes(2)) ? 2 : 1;
    const int nbh = nb * NH;

    for (int b0 = 0; b0 < NB; b0 += nb) {
        proj_kernel<<<dim3(nb * 32, 8, 3), dim3(256), 0, stream>>>(
            x, Wq, Wk, Wv, ws, b0, nbh);
        attn_kernel<<<dim3(16, nbh), dim3(256), 0, stream>>>(
            ws, out, b0, nbh);
    }
}

// Round 10
// 296.711 us; speedup vs baseline: 6.2741x; 1.1202x over previous
//
#include <hip/hip_runtime.h>
#include <hip/hip_bf16.h>

// MHA, softmax over model-dim AFTER A@V => plain accumulation, no online softmax.
// Round 10: proj data-movement overhaul. Round-9 post-mortem: proj 122us vs
// 7.7us MFMA floor — cost was per-block re-splitting of inputs (1.3G VALU),
// uncoalesced 16-row fragment gathers, and 50M scattered u16 epilogue stores.
// Fix: (1) one-time pre-split pass -> fragment-ordered bf16 hi/lo x & W in ws
// (5.77MB, linear loads, W L2-resident); (2) proj epilogue bounces through a
// 32KB LDS tile (block output is a contiguous 8192-elem ws region in ALL three
// layouts: base = tb + sl0*128) then flushes with coalesced 16B stores.
// Numerics bit-identical to round 9 (passed @ 3.9e-3). Attn byte-identical.

#define NB 4
#define NS 2048
#define ND 128
#define NH 8
#define EPB (NS * ND)        // 262144 elems per (b,h)
#define XFRAGS (512 * 4)     // x: 8192 rows /16 * 4 kc
#define WFRAGS (3 * 64 * 4)  // W: 3 tensors * (1024/16) * 4 kc
#define PS_ELEMS ((size_t)2 * XFRAGS * 512 + (size_t)2 * WFRAGS * 512)  // 2,883,584

typedef unsigned short u16;
typedef unsigned int u32;
typedef short bf16x8 __attribute__((ext_vector_type(8)));
typedef float f32x4 __attribute__((ext_vector_type(4)));

struct __align__(16) us8 { u16 u[8]; };

#define MFMA(a, b, c) __builtin_amdgcn_mfma_f32_16x16x32_bf16((a), (b), (c), 0, 0, 0)

__device__ __forceinline__ void splitf(float f, u16& hi, u16& lo) {
    u32 fb = __float_as_uint(f);
    u32 hb = fb + 0x7FFFu + ((fb >> 16) & 1u);      // RNE to bf16
    hi = (u16)(hb >> 16);
    float fh = __uint_as_float((hb >> 16) << 16);
    float fl = f - fh;                               // exact residual
    u32 lb = __float_as_uint(fl);
    u32 lr = lb + 0x7FFFu + ((lb >> 16) & 1u);
    lo = (u16)(lr >> 16);
}

// ---------------------------------------------------------------------------
// Pre-split: x -> A-frag-ordered XH/XL, W{q,k,v} -> B-frag-ordered WH/WL.
// Frag layout (verified by attn round 8): frag fi=(r16*4+kc), lane l, j:
// element (row r16*16+(l&15), k = kc*32+(l>>4)*8+j). Output writes are
// perfectly linear 16B per thread.
// ---------------------------------------------------------------------------
__global__ __launch_bounds__(256) void presplit_kernel(
    const float* __restrict__ xg, const float* __restrict__ Wqg,
    const float* __restrict__ Wkg, const float* __restrict__ Wvg,
    u16* __restrict__ ps)
{
    const int gid = blockIdx.x * 256 + threadIdx.x;
    const int total = (XFRAGS + WFRAGS) * 64;
    if (gid >= total) return;
    const int fi = gid >> 6, l = gid & 63;
    const float* src;
    u16 *H, *L;
    if (fi < XFRAGS) {
        const int m16 = fi >> 2, kc = fi & 3;
        src = xg + (size_t)(m16 * 16 + (l & 15)) * ND + kc * 32 + (l >> 4) * 8;
        H = ps + (size_t)fi * 512 + l * 8;
        L = H + (size_t)XFRAGS * 512;
    } else {
        const int wfi = fi - XFRAGS;
        const int e16g = wfi >> 2, kc = wfi & 3;
        const int t = e16g >> 6, e16 = e16g & 63;
        const float* Wt = (t == 0) ? Wqg : (t == 1) ? Wkg : Wvg;
        src = Wt + (size_t)(e16 * 16 + (l & 15)) * ND + kc * 32 + (l >> 4) * 8;
        H = ps + (size_t)2 * XFRAGS * 512 + (size_t)wfi * 512 + l * 8;
        L = H + (size_t)WFRAGS * 512;
    }
    float4 v0 = *(const float4*)src;
    float4 v1 = *(const float4*)(src + 4);
    float vv[8] = { v0.x, v0.y, v0.z, v0.w, v1.x, v1.y, v1.z, v1.w };
    us8 hh, ll;
    #pragma unroll
    for (int j = 0; j < 8; ++j) splitf(vv[j], hh.u[j], ll.u[j]);
    *(us8*)H = hh;
    *(us8*)L = ll;
}

// ---------------------------------------------------------------------------
// Projection: pure-bf16 3-term split MFMA GEMM from pre-split frags.
// Block 64s x 128e (one head), 4 waves (2s x 2e), wave 32s x 64e.
// Epilogue: split acc -> packed u32 -> LDS scatter -> coalesced 16B flush.
// ---------------------------------------------------------------------------
__global__ __launch_bounds__(256) void proj_kernel(
    const u16* __restrict__ ps, u16* __restrict__ ws, int b0, int nbh)
{
    __shared__ u32 sE[8192];   // 32KB epilogue bounce (block's contiguous region)

    const int which = blockIdx.z;
    const int tid = threadIdx.x;
    const int wv = tid >> 6;
    const int l  = tid & 63;
    const int c  = l & 15;
    const int g  = l >> 4;
    const int wr = wv & 1;
    const int wc = wv >> 1;
    const int bx = blockIdx.x;
    const int bgl = bx >> 5;               // batch within slice
    const int slb = (bx & 31) * 64;        // local s base within slice
    const int h = blockIdx.y;              // head (e-block = 128 wide = 1 head)
    const int m0 = (b0 + bgl) * NS + slb;  // global x row base

    const u16* XH = ps;
    const u16* XL = ps + (size_t)XFRAGS * 512;
    const u16* WH = ps + (size_t)2 * XFRAGS * 512;
    const u16* WL = WH + (size_t)WFRAGS * 512;

    // A-frags (hi/lo), linear loads
    const int m16b = (m0 >> 4) + wr * 2;
    bf16x8 ah[2][4], al[2][4];
    #pragma unroll
    for (int mi = 0; mi < 2; ++mi)
        #pragma unroll
        for (int kc = 0; kc < 4; ++kc) {
            size_t f = ((size_t)(m16b + mi) * 4 + kc) * 512 + l * 8;
            ah[mi][kc] = *(const bf16x8*)(XH + f);
            al[mi][kc] = *(const bf16x8*)(XL + f);
        }

    f32x4 acc[2][4];
    #pragma unroll
    for (int mi = 0; mi < 2; ++mi)
        #pragma unroll
        for (int ni = 0; ni < 4; ++ni) acc[mi][ni] = (f32x4){0.f, 0.f, 0.f, 0.f};

    const int e16b = which * 64 + h * 8 + wc * 4;   // concatenated W frag row base
    #pragma unroll
    for (int kc = 0; kc < 4; ++kc) {
        bf16x8 bh[4], bl[4];
        #pragma unroll
        for (int ni = 0; ni < 4; ++ni) {
            size_t f = ((size_t)(e16b + ni) * 4 + kc) * 512 + l * 8;
            bh[ni] = *(const bf16x8*)(WH + f);
            bl[ni] = *(const bf16x8*)(WL + f);
        }
        #pragma unroll
        for (int mi = 0; mi < 2; ++mi)
            #pragma unroll
            for (int ni = 0; ni < 4; ++ni) {
                acc[mi][ni] = MFMA(ah[mi][kc], bh[ni], acc[mi][ni]);
                acc[mi][ni] = MFMA(ah[mi][kc], bl[ni], acc[mi][ni]);
                acc[mi][ni] = MFMA(al[mi][kc], bh[ni], acc[mi][ni]);
            }
    }

    // scatter split accs into the block-region LDS tile
    #pragma unroll
    for (int mi = 0; mi < 2; ++mi)
        #pragma unroll
        for (int ni = 0; ni < 4; ++ni)
            #pragma unroll
            for (int r = 0; r < 4; ++r) {
                const int slL = wr * 32 + mi * 16 + 4 * g + r;   // 0..63
                const int d   = wc * 64 + ni * 16 + c;           // 0..127
                u16 ph, pl;
                splitf(acc[mi][ni][r], ph, pl);
                u32 off;
                if (which == 0)
                    off = (u32)(((slL >> 4) * 4 + (d >> 5)) * 512
                          + ((d >> 3) & 3) * 128 + (slL & 15) * 8 + (d & 7));
                else if (which == 1)
                    off = (u32)(((((slL >> 5) * 4 + (d >> 5)) * 2 + ((slL >> 4) & 1)) * 512)
                          + ((d >> 3) & 3) * 128 + (slL & 15) * 8 + (d & 7));
                else
                    off = (u32)(((slL >> 5) * 8 + (d >> 4)) * 512
                          + ((slL >> 3) & 3) * 128 + (d & 15) * 8 + (slL & 7));
                sE[off] = (u32)ph | ((u32)pl << 16);
            }
    __syncthreads();

    // coalesced flush: region base = tb + slb*128 in both hi and lo tensors
    const size_t TS = (size_t)nbh * EPB;
    const size_t tb = (size_t)(bgl * NH + h) * EPB;
    u16* HB = ws + (size_t)(2 * which) * TS + tb + (size_t)slb * 128;
    u16* LB = HB + TS;
    #pragma unroll
    for (int c4 = 0; c4 < 4; ++c4) {
        const int idx = c4 * 2048 + tid * 8;
        us8 hh, ll;
        #pragma unroll
        for (int j = 0; j < 8; ++j) {
            u32 v = sE[idx + j];
            hh.u[j] = (u16)(v & 0xFFFFu);
            ll.u[j] = (u16)(v >> 16);
        }
        *(us8*)(HB + idx) = hh;
        *(us8*)(LB + idx) = ll;
    }
}

// ---------------------------------------------------------------------------
// Attention: byte-identical to rounds 8/9 (verified).
// ---------------------------------------------------------------------------
__global__ __launch_bounds__(256, 2) void attn_kernel(
    const u16* __restrict__ ws, float* __restrict__ outg, int b0, int nbh)
{
    __shared__ __align__(16) u16 sbuf[2][4][4096];   // [dbuf][KH,KL,VH,VL][32t x 128d]
    __shared__ u32 sP[4][32 * 17];                   // per-wave per-mi P bounce

    const int tid = threadIdx.x;
    const int Wv = tid >> 6;
    const int l  = tid & 63;
    const int c  = l & 15;
    const int g  = l >> 4;
    const int bhl = blockIdx.y;
    const size_t tb = (size_t)bhl * EPB;
    const size_t TS = (size_t)nbh * EPB;

    const u16* QH = ws;
    const u16* QL = ws + 1 * TS;
    const u16* KH = ws + 2 * TS;
    const u16* KL = ws + 3 * TS;
    const u16* VH = ws + 4 * TS;
    const u16* VL = ws + 5 * TS;

    const int qb = blockIdx.x * 128 + Wv * 32;

    // Q fragments hi/lo (loop-invariant, registers)
    bf16x8 qh[2][4], ql[2][4];
    #pragma unroll
    for (int mi = 0; mi < 2; ++mi)
        #pragma unroll
        for (int kc = 0; kc < 4; ++kc) {
            size_t f = tb + ((size_t)(((qb + 16 * mi) >> 4) * 4 + kc) * 64 + l) * 8;
            qh[mi][kc] = *(const bf16x8*)(QH + f);
            ql[mi][kc] = *(const bf16x8*)(QL + f);
        }

    f32x4 z[2][8];
    #pragma unroll
    for (int mi = 0; mi < 2; ++mi)
        #pragma unroll
        for (int ni = 0; ni < 8; ++ni) z[mi][ni] = (f32x4){0.f, 0.f, 0.f, 0.f};

    const u16* srcs[4] = { KH, KL, VH, VL };
    auto stage = [&](int buf, int T) {
        #pragma unroll
        for (int t4 = 0; t4 < 4; ++t4)
            #pragma unroll
            for (int r = 0; r < 2; ++r)
                __builtin_amdgcn_global_load_lds(
                    (const __attribute__((address_space(1))) void*)
                        (srcs[t4] + tb + (size_t)T * 4096 + r * 2048 + tid * 8),
                    (__attribute__((address_space(3))) void*)
                        (&sbuf[buf][t4][r * 2048 + tid * 8]),
                    16, 0, 0);
    };

    u32* sPW = &sP[Wv][0];
    const float scale = 0.08838834764831845f;   // 1/sqrt(128)

    stage(0, 0);

    for (int T = 0; T < 64; ++T) {
        const int cur = T & 1;
        if (T < 63) {
            stage(cur ^ 1, T + 1);
            asm volatile("s_waitcnt vmcnt(8)" ::: "memory");   // cur tile landed
        } else {
            asm volatile("s_waitcnt vmcnt(0)" ::: "memory");
        }
        __builtin_amdgcn_s_barrier();
        asm volatile("" ::: "memory");

        const u16* bKH = &sbuf[cur][0][0];
        const u16* bKL = &sbuf[cur][1][0];
        const u16* bVH = &sbuf[cur][2][0];
        const u16* bVL = &sbuf[cur][3][0];

        // ---- QK^T: S = Qh*Kh + Qh*Kl + Ql*Kh (48 MFMAs) ----
        f32x4 s[2][2];
        #pragma unroll
        for (int mi = 0; mi < 2; ++mi)
            #pragma unroll
            for (int nt = 0; nt < 2; ++nt) s[mi][nt] = (f32x4){0.f, 0.f, 0.f, 0.f};
        __builtin_amdgcn_s_setprio(1);
        #pragma unroll
        for (int kc = 0; kc < 4; ++kc) {
            bf16x8 kh0 = *(const bf16x8*)(bKH + ((kc * 2 + 0) * 64 + l) * 8);
            bf16x8 kh1 = *(const bf16x8*)(bKH + ((kc * 2 + 1) * 64 + l) * 8);
            bf16x8 kl0 = *(const bf16x8*)(bKL + ((kc * 2 + 0) * 64 + l) * 8);
            bf16x8 kl1 = *(const bf16x8*)(bKL + ((kc * 2 + 1) * 64 + l) * 8);
            #pragma unroll
            for (int mi = 0; mi < 2; ++mi) {
                s[mi][0] = MFMA(qh[mi][kc], kh0, s[mi][0]);
                s[mi][0] = MFMA(qh[mi][kc], kl0, s[mi][0]);
                s[mi][0] = MFMA(ql[mi][kc], kh0, s[mi][0]);
                s[mi][1] = MFMA(qh[mi][kc], kh1, s[mi][1]);
                s[mi][1] = MFMA(qh[mi][kc], kl1, s[mi][1]);
                s[mi][1] = MFMA(ql[mi][kc], kh1, s[mi][1]);
            }
        }
        __builtin_amdgcn_s_setprio(0);

        // ---- per-mi P bounce: C-layout -> A-layout, bf16 hi/lo packed ----
        bf16x8 pa_h[2], pa_l[2];
        #pragma unroll
        for (int mi = 0; mi < 2; ++mi) {
            #pragma unroll
            for (int nt = 0; nt < 2; ++nt)
                #pragma unroll
                for (int r = 0; r < 4; ++r) {
                    float p = s[mi][nt][r] * scale;
                    u16 ph, pl; splitf(p, ph, pl);
                    sPW[(nt * 16 + c) * 17 + 4 * g + r] = (u32)ph | ((u32)pl << 16);
                }
            union { u16 uh[8]; bf16x8 v; } ph8;
            union { u16 ul[8]; bf16x8 v; } pl8;
            #pragma unroll
            for (int j = 0; j < 8; ++j) {
                u32 v = sPW[(8 * g + j) * 17 + c];
                ph8.uh[j] = (u16)(v & 0xFFFFu);
                pl8.ul[j] = (u16)(v >> 16);
            }
            pa_h[mi] = ph8.v;
            pa_l[mi] = pl8.v;
        }

        // ---- PV: Z += Ph*Vh + Ph*Vl + Pl*Vh (48 MFMAs) ----
        __builtin_amdgcn_s_setprio(1);
        #pragma unroll
        for (int ni = 0; ni < 8; ++ni) {
            bf16x8 vh = *(const bf16x8*)(bVH + (ni * 64 + l) * 8);
            bf16x8 vl = *(const bf16x8*)(bVL + (ni * 64 + l) * 8);
            #pragma unroll
            for (int mi = 0; mi < 2; ++mi) {
                z[mi][ni] = MFMA(pa_h[mi], vh, z[mi][ni]);
                z[mi][ni] = MFMA(pa_h[mi], vl, z[mi][ni]);
                z[mi][ni] = MFMA(pa_l[mi], vh, z[mi][ni]);
            }
        }
        __builtin_amdgcn_s_setprio(0);

        asm volatile("" ::: "memory");
        __builtin_amdgcn_s_barrier();   // all waves done with buf[cur] before restage
    }

    // ---- softmax over D=128 per q-row, fp32 store ----
    const size_t obase = (size_t)(b0 * NH + bhl) * EPB;
    #pragma unroll
    for (int mi = 0; mi < 2; ++mi)
        #pragma unroll
        for (int r = 0; r < 4; ++r) {
            float v[8];
            float m = -3.4e38f;
            #pragma unroll
            for (int ni = 0; ni < 8; ++ni) { v[ni] = z[mi][ni][r]; m = fmaxf(m, v[ni]); }
            #pragma unroll
            for (int off = 1; off < 16; off <<= 1) m = fmaxf(m, __shfl_xor(m, off, 64));
            float sum = 0.f;
            #pragma unroll
            for (int ni = 0; ni < 8; ++ni) { v[ni] = expf(v[ni] - m); sum += v[ni]; }
            #pragma unroll
            for (int off = 1; off < 16; off <<= 1) sum += __shfl_xor(sum, off, 64);
            const float inv = 1.f / sum;
            const int q = qb + 16 * mi + 4 * g + r;
            #pragma unroll
            for (int ni = 0; ni < 8; ++ni)
                outg[obase + (size_t)q * ND + ni * 16 + c] = v[ni] * inv;
        }
}

extern "C" void kernel_launch(void* const* d_in, const int* in_sizes, int n_in,
                              void* d_out, int out_size, void* d_ws, size_t ws_size,
                              hipStream_t stream)
{
    (void)out_size;
    int xi = 0;
    for (int i = 0; i < n_in && i < 4; ++i)
        if (in_sizes[i] == NB * NS * ND) { xi = i; break; }
    const float* x = (const float*)d_in[xi];
    const float* Wsp[3]; int w = 0;
    for (int i = 0; i < 4; ++i) if (i != xi) Wsp[w++] = (const float*)d_in[i];
    const float* Wq = Wsp[0];
    const float* Wk = Wsp[1];
    const float* Wv = Wsp[2];
    float* out = (float*)d_out;
    u16* ws = (u16*)d_ws;

    // need = 6 bf16 QKV tensors for nb batches + presplit region
    auto need_bytes = [](int nb) {
        return ((size_t)6 * nb * NH * EPB + PS_ELEMS) * 2;
    };
    int nb = (ws_size >= need_bytes(4)) ? 4 : (ws_size >= need_bytes(2)) ? 2 : 1;
    const int nbh = nb * NH;
    u16* psb = ws + (size_t)6 * nbh * EPB;   // presplit region after slice region

    // one-time input pre-split (same work every call)
    {
        const int total = (XFRAGS + WFRAGS) * 64;
        presplit_kernel<<<dim3((total + 255) / 256), dim3(256), 0, stream>>>(
            x, Wq, Wk, Wv, psb);
    }

    for (int b0 = 0; b0 < NB; b0 += nb) {
        proj_kernel<<<dim3(nb * 32, 8, 3), dim3(256), 0, stream>>>(
            psb, ws, b0, nbh);
        attn_kernel<<<dim3(16, nbh), dim3(256), 0, stream>>>(
            ws, out, b0, nbh);
    }
}